// Round 1
// baseline (158.739 us; speedup 1.0000x reference)
//
#include <hip/hip_runtime.h>
#include <hip/hip_bf16.h>

typedef __bf16 bf16x8 __attribute__((ext_vector_type(8)));
typedef float  f32x4  __attribute__((ext_vector_type(4)));

#define NB 16
#define NC 32
#define NH 32
#define NW 2048
#define NK (NC*NH)   // 1024

static __device__ __forceinline__ unsigned int pk2(float a, float b) {
    union { __bf16 h[2]; unsigned int u; } z;
    z.h[0] = (__bf16)a; z.h[1] = (__bf16)b;
    return z.u;
}

// ---------------------------------------------------------------------------
// Kernel 1: QKV projection.  q[b,o,w] = sum_k W[o,k] * X[b,k,w] + bias[o]
// Computed as O^T = X^T @ W^T with MFMA 16x16x32 bf16.
//   A-frag (X^T): lane row = w (lane&15), k = (lane>>4)*8+j  -> 8 strided
//                 global dword loads (64B-coalesced per 16-lane group).
//   B-frag (W^T): lane col = o (lane&15), k contiguous -> 2x float4 loads.
// Each wave: 32 w rows (2 mtiles) x all 96 outputs (6 ntiles). Block = 4 waves
// = 128 w. Grid = 16 batches x 16 tiles. x is read exactly once from HBM.
// Outputs qT,kT,vT as [B][W][32] bf16.
// ---------------------------------------------------------------------------
__global__ __launch_bounds__(256) void proj_kernel(
    const float* __restrict__ x,
    const float* __restrict__ wq, const float* __restrict__ bq,
    const float* __restrict__ wk, const float* __restrict__ bk,
    const float* __restrict__ wv, const float* __restrict__ bv,
    __bf16* __restrict__ qT, __bf16* __restrict__ kT, __bf16* __restrict__ vT)
{
    const int b    = blockIdx.x >> 4;
    const int wt   = blockIdx.x & 15;
    const int wave = threadIdx.x >> 6;
    const int lane = threadIdx.x & 63;
    const int g    = lane >> 4;
    const int lr   = lane & 15;
    const int w0   = wt * 128 + wave * 32;

    const float* xb = x + (size_t)b * NK * NW;
    const float* wptr[6] = { wq, wq + 16*NK, wk, wk + 16*NK, wv, wv + 16*NK };

    f32x4 acc[2][6];
    #pragma unroll
    for (int mt = 0; mt < 2; ++mt)
        #pragma unroll
        for (int nt = 0; nt < 6; ++nt)
            acc[mt][nt] = f32x4{0.f, 0.f, 0.f, 0.f};

    for (int kk = 0; kk < NK; kk += 32) {
        bf16x8 af[2];
        #pragma unroll
        for (int mt = 0; mt < 2; ++mt) {
            const float* p = xb + (size_t)(kk + g*8) * NW + (w0 + mt*16 + lr);
            bf16x8 t;
            #pragma unroll
            for (int j = 0; j < 8; ++j) t[j] = (__bf16)p[(size_t)j * NW];
            af[mt] = t;
        }
        bf16x8 bfv[6];
        #pragma unroll
        for (int nt = 0; nt < 6; ++nt) {
            const float* p = wptr[nt] + (size_t)lr * NK + kk + g*8;
            float4 lo = *(const float4*)p;
            float4 hi = *(const float4*)(p + 4);
            bf16x8 t;
            t[0]=(__bf16)lo.x; t[1]=(__bf16)lo.y; t[2]=(__bf16)lo.z; t[3]=(__bf16)lo.w;
            t[4]=(__bf16)hi.x; t[5]=(__bf16)hi.y; t[6]=(__bf16)hi.z; t[7]=(__bf16)hi.w;
            bfv[nt] = t;
        }
        #pragma unroll
        for (int mt = 0; mt < 2; ++mt)
            #pragma unroll
            for (int nt = 0; nt < 6; ++nt)
                acc[mt][nt] = __builtin_amdgcn_mfma_f32_16x16x32_bf16(
                    af[mt], bfv[nt], acc[mt][nt], 0, 0, 0);
    }

    // D layout: row (=w offset) = (lane>>4)*4 + r, col (=o offset) = lane&15.
    __bf16* outs[3] = { qT + (size_t)b*NW*NC, kT + (size_t)b*NW*NC, vT + (size_t)b*NW*NC };
    const float* biases[3] = { bq, bk, bv };
    #pragma unroll
    for (int nt = 0; nt < 6; ++nt) {
        __bf16* dst = outs[nt >> 1];
        const int o = (nt & 1) * 16 + lr;
        const float bb = biases[nt >> 1][o];
        #pragma unroll
        for (int mt = 0; mt < 2; ++mt) {
            #pragma unroll
            for (int r = 0; r < 4; ++r) {
                const int w = w0 + mt*16 + g*4 + r;
                dst[(size_t)w * NC + o] = (__bf16)(acc[mt][nt][r] + bb);
            }
        }
    }
}

// ---------------------------------------------------------------------------
// Kernel 1b: vT [B][W][32] -> V [B][32][W]  (tiny, 4 MiB total traffic)
// ---------------------------------------------------------------------------
__global__ __launch_bounds__(256) void vtrans_kernel(
    const __bf16* __restrict__ vT, __bf16* __restrict__ V)
{
    __shared__ __bf16 t[NC][136];
    const int b  = blockIdx.x >> 4;
    const int wc = blockIdx.x & 15;
    const int w0 = wc * 128;
    #pragma unroll
    for (int e = 0; e < 16; ++e) {
        int flat = e*256 + threadIdx.x;
        int wl = flat >> 5, c = flat & 31;
        t[c][wl] = vT[((size_t)b*NW + w0 + wl) * NC + c];
    }
    __syncthreads();
    #pragma unroll
    for (int e = 0; e < 16; ++e) {
        int flat = e*256 + threadIdx.x;
        int c = flat >> 7, wl = flat & 127;
        V[((size_t)b*NC + c) * NW + w0 + wl] = t[c][wl];
    }
}

// ---------------------------------------------------------------------------
// Kernel 2: flash attention + fused (broadcast-over-H residual) epilogue.
// Per wave: 16 query rows. Swapped QK^T: S^T = mfma(Kfrag, Qfrag) so each
// lane owns scores of ONE query row (w = lane&15), v = (lane>>4)*4+r.
// Online softmax, lane-local; row reduce = shfl_xor 16/32 (across dup groups).
// P redistributed with 8 shfls into the exact PV B-fragment (k = v = 8g+j).
// PV: O[c][w] = mfma(Vfrag[c][v], Pfrag). Epilogue: out = O/l + x over 32 h.
// No LDS, no barriers; waves fully independent.
// ---------------------------------------------------------------------------
__global__ __launch_bounds__(256) void attn_kernel(
    const float* __restrict__ x,
    const __bf16* __restrict__ qT, const __bf16* __restrict__ kT,
    const __bf16* __restrict__ V,
    float* __restrict__ out)
{
    const int b    = blockIdx.x >> 5;
    const int wt   = blockIdx.x & 31;
    const int wave = threadIdx.x >> 6;
    const int lane = threadIdx.x & 63;
    const int g = lane >> 4, lr = lane & 15;
    const int w0 = wt*64 + wave*16;

    const __bf16* qTb = qT + (size_t)b * NW * NC;
    const __bf16* kTb = kT + (size_t)b * NW * NC;
    const __bf16* Vb  = V  + (size_t)b * NC * NW;

    const bf16x8 qf = *(const bf16x8*)(qTb + (size_t)(w0 + lr) * NC + g*8);

    f32x4 acc0 = {0.f,0.f,0.f,0.f}, acc1 = {0.f,0.f,0.f,0.f};
    const f32x4 zc = {0.f,0.f,0.f,0.f};
    float m = -1e30f, lsum = 0.f;

    for (int v0 = 0; v0 < NW; v0 += 32) {
        bf16x8 kf0 = *(const bf16x8*)(kTb + (size_t)(v0 + lr)      * NC + g*8);
        bf16x8 kf1 = *(const bf16x8*)(kTb + (size_t)(v0 + 16 + lr) * NC + g*8);
        bf16x8 vf0 = *(const bf16x8*)(Vb + (size_t)lr      * NW + v0 + g*8);
        bf16x8 vf1 = *(const bf16x8*)(Vb + (size_t)(16+lr) * NW + v0 + g*8);

        f32x4 s0 = __builtin_amdgcn_mfma_f32_16x16x32_bf16(kf0, qf, zc, 0, 0, 0);
        f32x4 s1 = __builtin_amdgcn_mfma_f32_16x16x32_bf16(kf1, qf, zc, 0, 0, 0);

        // online softmax (per query row w = lane&15)
        float vm = fmaxf(fmaxf(fmaxf(s0[0],s0[1]), fmaxf(s0[2],s0[3])),
                         fmaxf(fmaxf(s1[0],s1[1]), fmaxf(s1[2],s1[3])));
        vm = fmaxf(vm, __shfl_xor(vm, 16));
        vm = fmaxf(vm, __shfl_xor(vm, 32));
        const float nm = fmaxf(m, vm);
        const float scale = __expf(m - nm);
        float p0[4], p1[4];
        float ps = 0.f;
        #pragma unroll
        for (int r = 0; r < 4; ++r) { p0[r] = __expf(s0[r] - nm); ps += p0[r]; }
        #pragma unroll
        for (int r = 0; r < 4; ++r) { p1[r] = __expf(s1[r] - nm); ps += p1[r]; }
        ps += __shfl_xor(ps, 16);
        ps += __shfl_xor(ps, 32);
        lsum = lsum * scale + ps;
        m = nm;
        #pragma unroll
        for (int r = 0; r < 4; ++r) { acc0[r] *= scale; acc1[r] *= scale; }

        // pack P to bf16 dwords: t0 covers vlocal quad g, t1 covers quad 4+g
        const unsigned int t0d0 = pk2(p0[0], p0[1]);
        const unsigned int t0d1 = pk2(p0[2], p0[3]);
        const unsigned int t1d0 = pk2(p1[0], p1[1]);
        const unsigned int t1d1 = pk2(p1[2], p1[3]);

        // B-frag lane needs vlocal 8g..8g+7 = quads (2g, 2g+1).
        const int qa = 2*g, qb = qa + 1;
        const int srcA = ((qa & 3) << 4) | lr;
        const int srcB = ((qb & 3) << 4) | lr;
        const unsigned int a0 = (unsigned int)__shfl((int)t0d0, srcA);
        const unsigned int a1 = (unsigned int)__shfl((int)t1d0, srcA);
        const unsigned int a2 = (unsigned int)__shfl((int)t0d1, srcA);
        const unsigned int a3 = (unsigned int)__shfl((int)t1d1, srcA);
        const unsigned int b0 = (unsigned int)__shfl((int)t0d0, srcB);
        const unsigned int b1 = (unsigned int)__shfl((int)t1d0, srcB);
        const unsigned int b2 = (unsigned int)__shfl((int)t0d1, srcB);
        const unsigned int b3 = (unsigned int)__shfl((int)t1d1, srcB);
        const bool sA = (qa >= 4), sB = (qb >= 4);
        union { unsigned int u[4]; bf16x8 v; } pu;
        pu.u[0] = sA ? a1 : a0;
        pu.u[1] = sA ? a3 : a2;
        pu.u[2] = sB ? b1 : b0;
        pu.u[3] = sB ? b3 : b2;

        acc0 = __builtin_amdgcn_mfma_f32_16x16x32_bf16(vf0, pu.v, acc0, 0, 0, 0);
        acc1 = __builtin_amdgcn_mfma_f32_16x16x32_bf16(vf1, pu.v, acc1, 0, 0, 0);
    }

    const float rl = 1.0f / lsum;
    const float* xb = x   + (size_t)b * NC * NH * NW;
    float*       ob = out + (size_t)b * NC * NH * NW;
    #pragma unroll
    for (int t = 0; t < 2; ++t) {
        #pragma unroll
        for (int r = 0; r < 4; ++r) {
            const float o = (t ? acc1[r] : acc0[r]) * rl;
            const int c = t*16 + g*4 + r;
            const float* xrow = xb + (size_t)c * NH * NW + w0 + lr;
            float*       orow = ob + (size_t)c * NH * NW + w0 + lr;
            #pragma unroll 4
            for (int h = 0; h < NH; ++h)
                orow[(size_t)h * NW] = o + xrow[(size_t)h * NW];
        }
    }
}

extern "C" void kernel_launch(void* const* d_in, const int* in_sizes, int n_in,
                              void* d_out, int out_size, void* d_ws, size_t ws_size,
                              hipStream_t stream)
{
    const float* x  = (const float*)d_in[0];
    const float* wq = (const float*)d_in[1];
    const float* bq = (const float*)d_in[2];
    const float* wk = (const float*)d_in[3];
    const float* bk = (const float*)d_in[4];
    const float* wv = (const float*)d_in[5];
    const float* bv = (const float*)d_in[6];
    float* out = (float*)d_out;

    // workspace layout (bf16): qT,kT,vT [B][W][32]; V [B][32][W] -- 8 MiB total
    char* ws = (char*)d_ws;
    __bf16* qT = (__bf16*)(ws);
    __bf16* kT = (__bf16*)(ws + (2u << 20));
    __bf16* vT = (__bf16*)(ws + (4u << 20));
    __bf16* V  = (__bf16*)(ws + (6u << 20));

    hipLaunchKernelGGL(proj_kernel, dim3(NB * 16), dim3(256), 0, stream,
                       x, wq, bq, wk, bk, wv, bv, qT, kT, vT);
    hipLaunchKernelGGL(vtrans_kernel, dim3(NB * 16), dim3(256), 0, stream, vT, V);
    hipLaunchKernelGGL(attn_kernel, dim3(NB * 32), dim3(256), 0, stream,
                       x, qT, kT, V, out);
}

// Round 2
// 117.798 us; speedup vs baseline: 1.3476x; 1.3476x over previous
//
#include <hip/hip_runtime.h>
#include <hip/hip_bf16.h>

typedef __bf16 bf16x8 __attribute__((ext_vector_type(8)));
typedef float  f32x4  __attribute__((ext_vector_type(4)));

#define NB 16
#define NC 32
#define NH 32
#define NW 2048
#define NK (NC*NH)   // 1024

static __device__ __forceinline__ unsigned int pk2(float a, float b) {
    union { __bf16 h[2]; unsigned int u; } z;
    z.h[0] = (__bf16)a; z.h[1] = (__bf16)b;
    return z.u;
}

// ---------------------------------------------------------------------------
// Kernel 0: convert weights to bf16 once (393 KB read, 196 KB write).
// wb layout: [3][32][1024] (q,k,v), same [o][k] flattening as the fp32 source.
// ---------------------------------------------------------------------------
__global__ __launch_bounds__(256) void wprep_kernel(
    const float* __restrict__ wq, const float* __restrict__ wk,
    const float* __restrict__ wv, __bf16* __restrict__ wb)
{
    const int i = blockIdx.x * 256 + threadIdx.x;        // 24576 float4 units
    const float* srcs[3] = { wq, wk, wv };
    const float4 v = *(const float4*)(srcs[i >> 13] + (size_t)(i & 8191) * 4);
    union { __bf16 h[4]; unsigned long long u; } z;
    z.h[0] = (__bf16)v.x; z.h[1] = (__bf16)v.y;
    z.h[2] = (__bf16)v.z; z.h[3] = (__bf16)v.w;
    *(unsigned long long*)(wb + (size_t)i * 4) = z.u;
}

// ---------------------------------------------------------------------------
// Kernel 1: QKV projection, 4-way K-split.
// Block = 256 threads (4 waves) covers 32 w; wave `ks` handles K slice
// [ks*256, ks*256+256) for both 16-row mtiles x all 6 output ntiles.
// Partial accs combined through LDS (exact fp32 adds). V is written directly
// in [B][C][W] layout (packed 8B stores) -- no separate transpose kernel.
// Grid = B * W/32 = 1024 blocks -> 4096 waves.
// ---------------------------------------------------------------------------
__global__ __launch_bounds__(256) void proj_kernel(
    const float* __restrict__ x, const __bf16* __restrict__ wb,
    const float* __restrict__ bq, const float* __restrict__ bk,
    const float* __restrict__ bv,
    __bf16* __restrict__ qT, __bf16* __restrict__ kT, __bf16* __restrict__ V)
{
    const int b    = blockIdx.x >> 6;
    const int wt   = blockIdx.x & 63;
    const int wave = threadIdx.x >> 6;       // = ks (K slice)
    const int lane = threadIdx.x & 63;
    const int g    = lane >> 4;
    const int lr   = lane & 15;
    const int w0   = wt * 32;

    const float* xb = x + (size_t)b * NK * NW;
    const int k0 = wave * 256;

    f32x4 acc[2][6];
    #pragma unroll
    for (int mt = 0; mt < 2; ++mt)
        #pragma unroll
        for (int nt = 0; nt < 6; ++nt)
            acc[mt][nt] = f32x4{0.f, 0.f, 0.f, 0.f};

    for (int ki = 0; ki < 8; ++ki) {
        const int kk = k0 + ki * 32;
        bf16x8 af[2];
        #pragma unroll
        for (int mt = 0; mt < 2; ++mt) {
            const float* p = xb + (size_t)(kk + g*8) * NW + (w0 + mt*16 + lr);
            bf16x8 t;
            #pragma unroll
            for (int j = 0; j < 8; ++j) t[j] = (__bf16)p[(size_t)j * NW];
            af[mt] = t;
        }
        bf16x8 bfv[6];
        #pragma unroll
        for (int nt = 0; nt < 6; ++nt)
            bfv[nt] = *(const bf16x8*)(wb + (size_t)(nt >> 1) * 32768
                                          + (size_t)((nt & 1) * 16 + lr) * NK
                                          + kk + g*8);
        #pragma unroll
        for (int mt = 0; mt < 2; ++mt)
            #pragma unroll
            for (int nt = 0; nt < 6; ++nt)
                acc[mt][nt] = __builtin_amdgcn_mfma_f32_16x16x32_bf16(
                    af[mt], bfv[nt], acc[mt][nt], 0, 0, 0);
    }

    // ---- combine the 4 K-slices through LDS ----
    __shared__ f32x4 part[4][12][64];   // 48 KB
    #pragma unroll
    for (int mt = 0; mt < 2; ++mt)
        #pragma unroll
        for (int nt = 0; nt < 6; ++nt)
            part[wave][mt*6 + nt][lane] = acc[mt][nt];
    __syncthreads();

    // wave -> (mtile, 3 ntiles): mt = wave&1, ntbase = (wave>>1)*3
    const int mt     = wave & 1;
    const int ntbase = (wave >> 1) * 3;
    const float* biases[3] = { bq, bk, bv };
    #pragma unroll
    for (int nti = 0; nti < 3; ++nti) {
        const int nt = ntbase + nti;
        const int fi = mt*6 + nt;
        f32x4 s = part[0][fi][lane];
        #pragma unroll
        for (int sl = 1; sl < 4; ++sl) s += part[sl][fi][lane];
        const int pid = nt >> 1;                 // 0=q,1=k,2=v
        const int o   = (nt & 1) * 16 + lr;
        const float bb = biases[pid][o];
        if (pid < 2) {
            __bf16* dst = (pid ? kT : qT) + (size_t)b * NW * NC;
            #pragma unroll
            for (int r = 0; r < 4; ++r) {
                const int w = w0 + mt*16 + g*4 + r;
                dst[(size_t)w * NC + o] = (__bf16)(s[r] + bb);
            }
        } else {
            union { __bf16 h[4]; unsigned long long u; } z;
            #pragma unroll
            for (int r = 0; r < 4; ++r) z.h[r] = (__bf16)(s[r] + bb);
            __bf16* dst = V + ((size_t)b * NC + o) * NW + (w0 + mt*16 + g*4);
            *(unsigned long long*)dst = z.u;
        }
    }
}

// ---------------------------------------------------------------------------
// Kernel 2: flash attention, 4-way KV-split + fused float4 epilogue.
// Block = 512 threads (8 waves) covers 32 query rows. Wave = (mt, ks):
// mtile mt (16 rows), KV slice ks (512 keys, 16 iters). Swapped QK^T so each
// lane owns one query row's scores; lane-local online softmax; 8-shfl P
// redistribution into the exact PV B-fragment. Partials merged in LDS
// (exact flash combine), final O staged in LDS, then block-wide float4
// epilogue: out = O + x broadcast over all 32 h rows.
// Grid = B * W/32 = 1024 blocks * 8 waves = 8192 waves (100% grid cap).
// ---------------------------------------------------------------------------
__global__ __launch_bounds__(512) void attn_kernel(
    const float* __restrict__ x,
    const __bf16* __restrict__ qT, const __bf16* __restrict__ kT,
    const __bf16* __restrict__ V,
    float* __restrict__ out)
{
    const int b    = blockIdx.x >> 6;
    const int wt   = blockIdx.x & 63;
    const int w0   = wt * 32;
    const int wave = threadIdx.x >> 6;        // 0..7
    const int lane = threadIdx.x & 63;
    const int g = lane >> 4, lr = lane & 15;
    const int mt = wave & 1;
    const int ks = wave >> 1;
    const int wq0 = w0 + mt * 16;

    const __bf16* qTb = qT + (size_t)b * NW * NC;
    const __bf16* kTb = kT + (size_t)b * NW * NC;
    const __bf16* Vb  = V  + (size_t)b * NC * NW;

    const bf16x8 qf = *(const bf16x8*)(qTb + (size_t)(wq0 + lr) * NC + g*8);

    f32x4 acc0 = {0.f,0.f,0.f,0.f}, acc1 = {0.f,0.f,0.f,0.f};
    const f32x4 zc = {0.f,0.f,0.f,0.f};
    float m = -1e30f, lsum = 0.f;

    const int vbeg = ks * 512, vend = vbeg + 512;
    for (int v0 = vbeg; v0 < vend; v0 += 32) {
        bf16x8 kf0 = *(const bf16x8*)(kTb + (size_t)(v0 + lr)      * NC + g*8);
        bf16x8 kf1 = *(const bf16x8*)(kTb + (size_t)(v0 + 16 + lr) * NC + g*8);
        bf16x8 vf0 = *(const bf16x8*)(Vb + (size_t)lr      * NW + v0 + g*8);
        bf16x8 vf1 = *(const bf16x8*)(Vb + (size_t)(16+lr) * NW + v0 + g*8);

        f32x4 s0 = __builtin_amdgcn_mfma_f32_16x16x32_bf16(kf0, qf, zc, 0, 0, 0);
        f32x4 s1 = __builtin_amdgcn_mfma_f32_16x16x32_bf16(kf1, qf, zc, 0, 0, 0);

        float vm = fmaxf(fmaxf(fmaxf(s0[0],s0[1]), fmaxf(s0[2],s0[3])),
                         fmaxf(fmaxf(s1[0],s1[1]), fmaxf(s1[2],s1[3])));
        vm = fmaxf(vm, __shfl_xor(vm, 16));
        vm = fmaxf(vm, __shfl_xor(vm, 32));
        const float nm = fmaxf(m, vm);
        const float scale = __expf(m - nm);
        float p0[4], p1[4];
        float ps = 0.f;
        #pragma unroll
        for (int r = 0; r < 4; ++r) { p0[r] = __expf(s0[r] - nm); ps += p0[r]; }
        #pragma unroll
        for (int r = 0; r < 4; ++r) { p1[r] = __expf(s1[r] - nm); ps += p1[r]; }
        ps += __shfl_xor(ps, 16);
        ps += __shfl_xor(ps, 32);
        lsum = lsum * scale + ps;
        m = nm;
        #pragma unroll
        for (int r = 0; r < 4; ++r) { acc0[r] *= scale; acc1[r] *= scale; }

        const unsigned int t0d0 = pk2(p0[0], p0[1]);
        const unsigned int t0d1 = pk2(p0[2], p0[3]);
        const unsigned int t1d0 = pk2(p1[0], p1[1]);
        const unsigned int t1d1 = pk2(p1[2], p1[3]);

        const int qa = 2*g, qb = qa + 1;
        const int srcA = ((qa & 3) << 4) | lr;
        const int srcB = ((qb & 3) << 4) | lr;
        const unsigned int a0 = (unsigned int)__shfl((int)t0d0, srcA);
        const unsigned int a1 = (unsigned int)__shfl((int)t1d0, srcA);
        const unsigned int a2 = (unsigned int)__shfl((int)t0d1, srcA);
        const unsigned int a3 = (unsigned int)__shfl((int)t1d1, srcA);
        const unsigned int b0 = (unsigned int)__shfl((int)t0d0, srcB);
        const unsigned int b1 = (unsigned int)__shfl((int)t1d0, srcB);
        const unsigned int b2 = (unsigned int)__shfl((int)t0d1, srcB);
        const unsigned int b3 = (unsigned int)__shfl((int)t1d1, srcB);
        const bool sA = (qa >= 4), sB = (qb >= 4);
        union { unsigned int u[4]; bf16x8 v; } pu;
        pu.u[0] = sA ? a1 : a0;
        pu.u[1] = sA ? a3 : a2;
        pu.u[2] = sB ? b1 : b0;
        pu.u[3] = sB ? b3 : b2;

        acc0 = __builtin_amdgcn_mfma_f32_16x16x32_bf16(vf0, pu.v, acc0, 0, 0, 0);
        acc1 = __builtin_amdgcn_mfma_f32_16x16x32_bf16(vf1, pu.v, acc1, 0, 0, 0);
    }

    // ---- merge the 4 KV slices (exact flash combine) ----
    __shared__ float sm[8][16];
    __shared__ float sl[8][16];
    __shared__ float sO[8][32][17];     // padded to kill bank conflicts
    __shared__ float Of[32][33];        // final O/l, [c][w-local], padded

    if (g == 0) { sm[wave][lr] = m; sl[wave][lr] = lsum; }
    #pragma unroll
    for (int t = 0; t < 2; ++t)
        #pragma unroll
        for (int r = 0; r < 4; ++r)
            sO[wave][t*16 + g*4 + r][lr] = (t ? acc1 : acc0)[r];
    __syncthreads();

    if (ks == 0) {
        float ms[4];
        #pragma unroll
        for (int s = 0; s < 4; ++s) ms[s] = sm[2*s + mt][lr];
        float M = fmaxf(fmaxf(ms[0], ms[1]), fmaxf(ms[2], ms[3]));
        float f[4]; float L = 0.f;
        #pragma unroll
        for (int s = 0; s < 4; ++s) { f[s] = __expf(ms[s] - M); L += sl[2*s + mt][lr] * f[s]; }
        const float rL = 1.0f / L;
        #pragma unroll
        for (int t = 0; t < 2; ++t)
            #pragma unroll
            for (int r = 0; r < 4; ++r) {
                const int c = t*16 + g*4 + r;
                float o = 0.f;
                #pragma unroll
                for (int s = 0; s < 4; ++s) o += sO[2*s + mt][c][lr] * f[s];
                Of[c][mt*16 + lr] = o * rL;
            }
    }
    __syncthreads();

    // ---- block-wide epilogue: out[b,c,h,w0..w0+31] = Of[c][.] + x ----
    const float* xb = x   + (size_t)b * NC * NH * NW + w0;
    float*       ob = out + (size_t)b * NC * NH * NW + w0;
    const int chunk = threadIdx.x & 7;          // 4 floats each
    #pragma unroll
    for (int it = 0; it < 16; ++it) {
        const int row = it*64 + (threadIdx.x >> 3);   // 0..1023 = c*32+h
        const int c = row >> 5, h = row & 31;
        const size_t off = ((size_t)c * NH + h) * NW + chunk*4;
        const float4 xv = *(const float4*)(xb + off);
        float4 ov;
        ov.x = Of[c][chunk*4 + 0] + xv.x;
        ov.y = Of[c][chunk*4 + 1] + xv.y;
        ov.z = Of[c][chunk*4 + 2] + xv.z;
        ov.w = Of[c][chunk*4 + 3] + xv.w;
        *(float4*)(ob + off) = ov;
    }
}

extern "C" void kernel_launch(void* const* d_in, const int* in_sizes, int n_in,
                              void* d_out, int out_size, void* d_ws, size_t ws_size,
                              hipStream_t stream)
{
    const float* x  = (const float*)d_in[0];
    const float* wq = (const float*)d_in[1];
    const float* bq = (const float*)d_in[2];
    const float* wk = (const float*)d_in[3];
    const float* bk = (const float*)d_in[4];
    const float* wv = (const float*)d_in[5];
    const float* bv = (const float*)d_in[6];
    float* out = (float*)d_out;

    // ws layout (bf16): qT [B][W][32] @0, kT @2MB, V [B][32][W] @4MB, wb @6MB
    char* ws = (char*)d_ws;
    __bf16* qT = (__bf16*)(ws);
    __bf16* kT = (__bf16*)(ws + (2u << 20));
    __bf16* V  = (__bf16*)(ws + (4u << 20));
    __bf16* wb = (__bf16*)(ws + (6u << 20));

    hipLaunchKernelGGL(wprep_kernel, dim3(96), dim3(256), 0, stream, wq, wk, wv, wb);
    hipLaunchKernelGGL(proj_kernel, dim3(NB * 64), dim3(256), 0, stream,
                       x, wb, bq, bk, bv, qT, kT, V);
    hipLaunchKernelGGL(attn_kernel, dim3(NB * 64), dim3(512), 0, stream,
                       x, qT, kT, V, out);
}

// Round 4
// 106.688 us; speedup vs baseline: 1.4879x; 1.1041x over previous
//
#include <hip/hip_runtime.h>
#include <hip/hip_bf16.h>

typedef __bf16 bf16x8 __attribute__((ext_vector_type(8)));
typedef float  f32x4  __attribute__((ext_vector_type(4)));
typedef float  f32x16 __attribute__((ext_vector_type(16)));

#define NB 16
#define NC 32
#define NH 32
#define NW 2048
#define NK (NC*NH)   // 1024

static __device__ __forceinline__ unsigned int pk2(float a, float b) {
    union { __bf16 h[2]; unsigned int u; } z;
    z.h[0] = (__bf16)a; z.h[1] = (__bf16)b;
    return z.u;
}

// ---------------------------------------------------------------------------
// Kernel 0: weights -> bf16. wb layout [3][32][1024].
// ---------------------------------------------------------------------------
__global__ __launch_bounds__(256) void wprep_kernel(
    const float* __restrict__ wq, const float* __restrict__ wk,
    const float* __restrict__ wv, __bf16* __restrict__ wb)
{
    const int i = blockIdx.x * 256 + threadIdx.x;        // 24576 float4 units
    const float* srcs[3] = { wq, wk, wv };
    const float4 v = *(const float4*)(srcs[i >> 13] + (size_t)(i & 8191) * 4);
    union { __bf16 h[4]; unsigned long long u; } z;
    z.h[0] = (__bf16)v.x; z.h[1] = (__bf16)v.y;
    z.h[2] = (__bf16)v.z; z.h[3] = (__bf16)v.w;
    *(unsigned long long*)(wb + (size_t)i * 4) = z.u;
}

// ---------------------------------------------------------------------------
// Kernel 1: QKV projection, 4-way K-split, two-round LDS combine (24 KB).
// ---------------------------------------------------------------------------
__global__ __launch_bounds__(256, 4) void proj_kernel(
    const float* __restrict__ x, const __bf16* __restrict__ wb,
    const float* __restrict__ bq, const float* __restrict__ bk,
    const float* __restrict__ bv,
    __bf16* __restrict__ qT, __bf16* __restrict__ kT, __bf16* __restrict__ V)
{
    const int b    = blockIdx.x >> 6;
    const int wt   = blockIdx.x & 63;
    const int wave = threadIdx.x >> 6;       // = K slice
    const int lane = threadIdx.x & 63;
    const int g    = lane >> 4;
    const int lr   = lane & 15;
    const int w0   = wt * 32;

    const float* xb = x + (size_t)b * NK * NW;
    const int k0 = wave * 256;

    f32x4 acc[2][6];
    #pragma unroll
    for (int mt = 0; mt < 2; ++mt)
        #pragma unroll
        for (int nt = 0; nt < 6; ++nt)
            acc[mt][nt] = f32x4{0.f, 0.f, 0.f, 0.f};

    for (int ki = 0; ki < 8; ++ki) {
        const int kk = k0 + ki * 32;
        bf16x8 af[2];
        #pragma unroll
        for (int mt = 0; mt < 2; ++mt) {
            const float* p = xb + (size_t)(kk + g*8) * NW + (w0 + mt*16 + lr);
            bf16x8 t;
            #pragma unroll
            for (int j = 0; j < 8; ++j) t[j] = (__bf16)p[(size_t)j * NW];
            af[mt] = t;
        }
        bf16x8 bfv[6];
        #pragma unroll
        for (int nt = 0; nt < 6; ++nt)
            bfv[nt] = *(const bf16x8*)(wb + (size_t)(nt >> 1) * 32768
                                          + (size_t)((nt & 1) * 16 + lr) * NK
                                          + kk + g*8);
        #pragma unroll
        for (int mt = 0; mt < 2; ++mt)
            #pragma unroll
            for (int nt = 0; nt < 6; ++nt)
                acc[mt][nt] = __builtin_amdgcn_mfma_f32_16x16x32_bf16(
                    af[mt], bfv[nt], acc[mt][nt], 0, 0, 0);
    }

    // ---- combine the 4 K-slices, two mt-rounds through 24 KB of LDS ----
    __shared__ f32x4 part[4][6][64];
    const float* biases[3] = { bq, bk, bv };
    #pragma unroll
    for (int mt = 0; mt < 2; ++mt) {
        if (mt) __syncthreads();
        #pragma unroll
        for (int nt = 0; nt < 6; ++nt)
            part[wave][nt][lane] = acc[mt][nt];
        __syncthreads();
        #pragma unroll
        for (int q = 0; q < 2; ++q) {
            const int nt = wave + q * 4;
            if (nt < 6) {
                f32x4 s = part[0][nt][lane];
                #pragma unroll
                for (int sl = 1; sl < 4; ++sl) s += part[sl][nt][lane];
                const int pid = nt >> 1;             // 0=q,1=k,2=v
                const int o   = (nt & 1) * 16 + lr;
                const float bb = biases[pid][o];
                if (pid < 2) {
                    __bf16* dst = (pid ? kT : qT) + (size_t)b * NW * NC;
                    #pragma unroll
                    for (int r = 0; r < 4; ++r) {
                        const int w = w0 + mt*16 + g*4 + r;
                        dst[(size_t)w * NC + o] = (__bf16)(s[r] + bb);
                    }
                } else {
                    union { __bf16 h[4]; unsigned long long u; } z;
                    #pragma unroll
                    for (int r = 0; r < 4; ++r) z.h[r] = (__bf16)(s[r] + bb);
                    __bf16* dst = V + ((size_t)b * NC + o) * NW + (w0 + mt*16 + g*4);
                    *(unsigned long long*)dst = z.u;
                }
            }
        }
    }
}

// ---------------------------------------------------------------------------
// Kernel 2: flash attention on 32x32x16 MFMA.
// K rows fed to QK^T are sigma-permuted (swap row-quads 1<->2, 5<->6) so that
// S output row m carries v = sigma(m); with the C/D map
// row=(r&3)+8*(r>>2)+4*hi this makes each lane's 16 scores v-CONTIGUOUS:
// hi=0 owns v {0..7,16..23}, hi=1 owns {8..15,24..31} == exactly the PV
// B-fragment slots (k=8*hi+j). P assembly = 8 local pk2, ZERO cross-lane ops.
// Cross-half max/sum via __shfl_xor(.,32) (2 LDS-pipe ops/iter, verified).
// Block = 8 waves x 256-key slices over 32 query rows; LDS merge + fused
// float4 epilogue (out = O + x broadcast over h).
// ---------------------------------------------------------------------------
__global__ __launch_bounds__(512) void attn_kernel(
    const float* __restrict__ x,
    const __bf16* __restrict__ qT, const __bf16* __restrict__ kT,
    const __bf16* __restrict__ V,
    float* __restrict__ out)
{
    const int b    = blockIdx.x >> 6;
    const int wt   = blockIdx.x & 63;
    const int w0   = wt * 32;
    const int wave = threadIdx.x >> 6;        // KV slice 0..7
    const int lane = threadIdx.x & 63;
    const int wl = lane & 31, hi = lane >> 5;
    // sigma: swap bits 2 and 3 of wl (row-quad 1<->2, 5<->6)
    const int swl = (wl & 0x13) | ((wl & 4) << 1) | ((wl & 8) >> 1);

    const __bf16* qTb = qT + (size_t)b * NW * NC;
    const __bf16* kTb = kT + (size_t)b * NW * NC;
    const __bf16* Vb  = V  + (size_t)b * NC * NW;

    // Q fragments (B-operand): col n = w0+wl, channel slots c = 8*hi+j (+16)
    const __bf16* qrow = qTb + (size_t)(w0 + wl) * NC;
    const bf16x8 qf0 = *(const bf16x8*)(qrow + hi*8);
    const bf16x8 qf1 = *(const bf16x8*)(qrow + 16 + hi*8);

    f32x16 acc, z16;
    #pragma unroll
    for (int r = 0; r < 16; ++r) { acc[r] = 0.f; z16[r] = 0.f; }
    float m = -1e30f, lsum = 0.f;

    const int vbeg = wave * 256;
    for (int it = 0; it < 8; ++it) {
        const int v0 = vbeg + it * 32;
        const __bf16* krow = kTb + (size_t)(v0 + swl) * NC;   // sigma-permuted
        const bf16x8 kf0 = *(const bf16x8*)(krow + hi*8);
        const bf16x8 kf1 = *(const bf16x8*)(krow + 16 + hi*8);
        const __bf16* vrow = Vb + (size_t)wl * NW + v0;
        const bf16x8 vf0 = *(const bf16x8*)(vrow + hi*8);
        const bf16x8 vf1 = *(const bf16x8*)(vrow + 16 + hi*8);

        f32x16 s = __builtin_amdgcn_mfma_f32_32x32x16_bf16(kf0, qf0, z16, 0, 0, 0);
        s = __builtin_amdgcn_mfma_f32_32x32x16_bf16(kf1, qf1, s, 0, 0, 0);
        // lane (wl,hi) now holds P-scores for v-set: p[r] <-> v = (hi? 8:0)+r
        // for r<8, and v = 16+(hi?8:0)+(r-8) for r>=8  (v-contiguous blocks)

        // ---- online softmax over v for this lane's query column ----
        float tm[8];
        #pragma unroll
        for (int r = 0; r < 8; ++r) tm[r] = fmaxf(s[r], s[r+8]);
        #pragma unroll
        for (int r = 0; r < 4; ++r) tm[r] = fmaxf(tm[r], tm[r+4]);
        float vm = fmaxf(fmaxf(tm[0], tm[1]), fmaxf(tm[2], tm[3]));
        vm = fmaxf(vm, __shfl_xor(vm, 32));
        const float nm = fmaxf(m, vm);
        const float sc = __expf(m - nm);
        float p[16];
        #pragma unroll
        for (int r = 0; r < 16; ++r) p[r] = __expf(s[r] - nm);
        float ts[8];
        #pragma unroll
        for (int r = 0; r < 8; ++r) ts[r] = p[r] + p[r+8];
        #pragma unroll
        for (int r = 0; r < 4; ++r) ts[r] += ts[r+4];
        float ps = (ts[0] + ts[1]) + (ts[2] + ts[3]);
        ps += __shfl_xor(ps, 32);
        lsum = lsum * sc + ps;
        m = nm;
        #pragma unroll
        for (int r = 0; r < 16; ++r) acc[r] *= sc;

        // ---- PV B-fragments: purely lane-local after the sigma trick ----
        union { unsigned int u[4]; bf16x8 v; } pf1, pf2;
        #pragma unroll
        for (int i = 0; i < 4; ++i) pf1.u[i] = pk2(p[2*i],     p[2*i + 1]);
        #pragma unroll
        for (int i = 0; i < 4; ++i) pf2.u[i] = pk2(p[8 + 2*i], p[8 + 2*i + 1]);

        acc = __builtin_amdgcn_mfma_f32_32x32x16_bf16(vf0, pf1.v, acc, 0, 0, 0);
        acc = __builtin_amdgcn_mfma_f32_32x32x16_bf16(vf1, pf2.v, acc, 0, 0, 0);
    }

    // ---- merge the 8 KV slices (exact flash combine) ----
    __shared__ float sm[8][32];
    __shared__ float sl[8][32];
    __shared__ float sO[8][32][33];
    __shared__ float Of[32][33];

    if (hi == 0) { sm[wave][wl] = m; sl[wave][wl] = lsum; }
    #pragma unroll
    for (int r = 0; r < 16; ++r) {
        const int c = (r & 3) + 8*(r >> 2) + 4*hi;
        sO[wave][c][wl] = acc[r];
    }
    __syncthreads();

    {
        const int w  = threadIdx.x & 31;
        const int c0 = (threadIdx.x >> 5) * 2;
        float ms[8], ls[8], f[8];
        #pragma unroll
        for (int s = 0; s < 8; ++s) { ms[s] = sm[s][w]; ls[s] = sl[s][w]; }
        float M = ms[0];
        #pragma unroll
        for (int s = 1; s < 8; ++s) M = fmaxf(M, ms[s]);
        float L = 0.f;
        #pragma unroll
        for (int s = 0; s < 8; ++s) { f[s] = __expf(ms[s] - M); L += ls[s] * f[s]; }
        const float rL = 1.0f / L;
        #pragma unroll
        for (int cc = 0; cc < 2; ++cc) {
            float o = 0.f;
            #pragma unroll
            for (int s = 0; s < 8; ++s) o += sO[s][c0 + cc][w] * f[s];
            Of[c0 + cc][w] = o * rL;
        }
    }
    __syncthreads();

    // ---- block-wide epilogue: out[b,c,h,w0..w0+31] = Of[c][.] + x ----
    const float* xb = x   + (size_t)b * NC * NH * NW + w0;
    float*       ob = out + (size_t)b * NC * NH * NW + w0;
    const int chunk = threadIdx.x & 7;          // 4 floats each
    #pragma unroll
    for (int it = 0; it < 16; ++it) {
        const int row = it*64 + (threadIdx.x >> 3);   // 0..1023 = c*32+h
        const int c = row >> 5, h = row & 31;
        const size_t off = ((size_t)c * NH + h) * NW + chunk*4;
        const float4 xv = *(const float4*)(xb + off);
        float4 ov;
        ov.x = Of[c][chunk*4 + 0] + xv.x;
        ov.y = Of[c][chunk*4 + 1] + xv.y;
        ov.z = Of[c][chunk*4 + 2] + xv.z;
        ov.w = Of[c][chunk*4 + 3] + xv.w;
        *(float4*)(ob + off) = ov;
    }
}

extern "C" void kernel_launch(void* const* d_in, const int* in_sizes, int n_in,
                              void* d_out, int out_size, void* d_ws, size_t ws_size,
                              hipStream_t stream)
{
    const float* x  = (const float*)d_in[0];
    const float* wq = (const float*)d_in[1];
    const float* bq = (const float*)d_in[2];
    const float* wk = (const float*)d_in[3];
    const float* bk = (const float*)d_in[4];
    const float* wv = (const float*)d_in[5];
    const float* bv = (const float*)d_in[6];
    float* out = (float*)d_out;

    // ws layout (bf16): qT [B][W][32] @0, kT @2MB, V [B][32][W] @4MB, wb @6MB
    char* ws = (char*)d_ws;
    __bf16* qT = (__bf16*)(ws);
    __bf16* kT = (__bf16*)(ws + (2u << 20));
    __bf16* V  = (__bf16*)(ws + (4u << 20));
    __bf16* wb = (__bf16*)(ws + (6u << 20));

    hipLaunchKernelGGL(wprep_kernel, dim3(96), dim3(256), 0, stream, wq, wk, wv, wb);
    hipLaunchKernelGGL(proj_kernel, dim3(NB * 64), dim3(256), 0, stream,
                       x, wb, bq, bk, bv, qT, kT, V);
    hipLaunchKernelGGL(attn_kernel, dim3(NB * 64), dim3(512), 0, stream,
                       x, qT, kT, V, out);
}

// Round 5
// 102.877 us; speedup vs baseline: 1.5430x; 1.0370x over previous
//
#include <hip/hip_runtime.h>
#include <hip/hip_bf16.h>

typedef __bf16 bf16x8 __attribute__((ext_vector_type(8)));
typedef float  f32x4  __attribute__((ext_vector_type(4)));
typedef float  f32x16 __attribute__((ext_vector_type(16)));

#define NB 16
#define NC 32
#define NH 32
#define NW 2048
#define NK (NC*NH)   // 1024

static __device__ __forceinline__ unsigned int pk2(float a, float b) {
    union { __bf16 h[2]; unsigned int u; } z;
    z.h[0] = (__bf16)a; z.h[1] = (__bf16)b;
    return z.u;
}

// ---------------------------------------------------------------------------
// Kernel 0: weights -> bf16. wb layout [3][32][1024].
// ---------------------------------------------------------------------------
__global__ __launch_bounds__(256) void wprep_kernel(
    const float* __restrict__ wq, const float* __restrict__ wk,
    const float* __restrict__ wv, __bf16* __restrict__ wb)
{
    const int i = blockIdx.x * 256 + threadIdx.x;        // 24576 float4 units
    const float* srcs[3] = { wq, wk, wv };
    const float4 v = *(const float4*)(srcs[i >> 13] + (size_t)(i & 8191) * 4);
    union { __bf16 h[4]; unsigned long long u; } z;
    z.h[0] = (__bf16)v.x; z.h[1] = (__bf16)v.y;
    z.h[2] = (__bf16)v.z; z.h[3] = (__bf16)v.w;
    *(unsigned long long*)(wb + (size_t)i * 4) = z.u;
}

// ---------------------------------------------------------------------------
// Kernel 1: QKV projection, 4-way K-split.
// Interleaved-mtile A loads: mtile-row t maps to w = w0 + 2*t + mt, so ONE
// float2 load per lane per j feeds BOTH mtiles' A-fragments (8x8B loads per
// K-step; each instruction = four full 128B cache lines). Manual 2-deep
// register double-buffer keeps the next K-step's loads in flight during MFMA.
// No launch_bounds min-waves clamp (R4's VGPR=52 serialized the loads).
// Two-round LDS combine (24 KB) as in R4, with the stride-2 w remap on store.
// ---------------------------------------------------------------------------
__global__ __launch_bounds__(256) void proj_kernel(
    const float* __restrict__ x, const __bf16* __restrict__ wb,
    const float* __restrict__ bq, const float* __restrict__ bk,
    const float* __restrict__ bv,
    __bf16* __restrict__ qT, __bf16* __restrict__ kT, __bf16* __restrict__ V)
{
    const int b    = blockIdx.x >> 6;
    const int wt   = blockIdx.x & 63;
    const int wave = threadIdx.x >> 6;       // = K slice
    const int lane = threadIdx.x & 63;
    const int g    = lane >> 4;
    const int lr   = lane & 15;
    const int w0   = wt * 32;

    const float* xb = x + (size_t)b * NK * NW;
    const int k0 = wave * 256;
    const float* xcol = xb + (w0 + 2*lr);    // column base for this lane

    f32x4 acc[2][6];
    #pragma unroll
    for (int mt = 0; mt < 2; ++mt)
        #pragma unroll
        for (int nt = 0; nt < 6; ++nt)
            acc[mt][nt] = f32x4{0.f, 0.f, 0.f, 0.f};

    float2 A0[8], A1[8];

#define LOADA(DST, KK)                                                        \
    _Pragma("unroll")                                                         \
    for (int j = 0; j < 8; ++j)                                               \
        DST[j] = *(const float2*)(xcol + (size_t)((KK) + g*8 + j) * NW);

#define COMPUTE(SRC, KK)                                                      \
    {                                                                         \
        bf16x8 af0, af1;                                                      \
        _Pragma("unroll")                                                     \
        for (int j = 0; j < 8; ++j) { af0[j] = (__bf16)SRC[j].x;              \
                                      af1[j] = (__bf16)SRC[j].y; }            \
        bf16x8 bfv[6];                                                        \
        _Pragma("unroll")                                                     \
        for (int nt = 0; nt < 6; ++nt)                                        \
            bfv[nt] = *(const bf16x8*)(wb + (size_t)(nt >> 1) * 32768         \
                                          + (size_t)((nt & 1) * 16 + lr) * NK \
                                          + (KK) + g*8);                      \
        _Pragma("unroll")                                                     \
        for (int nt = 0; nt < 6; ++nt) {                                      \
            acc[0][nt] = __builtin_amdgcn_mfma_f32_16x16x32_bf16(             \
                af0, bfv[nt], acc[0][nt], 0, 0, 0);                           \
            acc[1][nt] = __builtin_amdgcn_mfma_f32_16x16x32_bf16(             \
                af1, bfv[nt], acc[1][nt], 0, 0, 0);                           \
        }                                                                     \
    }

    LOADA(A0, k0);
    #pragma unroll
    for (int kp = 0; kp < 4; ++kp) {
        const int kk0 = k0 + (2*kp)     * 32;
        const int kk1 = k0 + (2*kp + 1) * 32;
        LOADA(A1, kk1);
        COMPUTE(A0, kk0);
        if (kp < 3) { LOADA(A0, kk1 + 32); }
        COMPUTE(A1, kk1);
    }
#undef LOADA
#undef COMPUTE

    // ---- combine the 4 K-slices, two mt-rounds through 24 KB of LDS ----
    __shared__ f32x4 part[4][6][64];
    const float* biases[3] = { bq, bk, bv };
    #pragma unroll
    for (int mt = 0; mt < 2; ++mt) {
        if (mt) __syncthreads();
        #pragma unroll
        for (int nt = 0; nt < 6; ++nt)
            part[wave][nt][lane] = acc[mt][nt];
        __syncthreads();
        #pragma unroll
        for (int q = 0; q < 2; ++q) {
            const int nt = wave + q * 4;
            if (nt < 6) {
                f32x4 s = part[0][nt][lane];
                #pragma unroll
                for (int sl = 1; sl < 4; ++sl) s += part[sl][nt][lane];
                const int pid = nt >> 1;             // 0=q,1=k,2=v
                const int o   = (nt & 1) * 16 + lr;
                const float bb = biases[pid][o];
                if (pid < 2) {
                    __bf16* dst = (pid ? kT : qT) + (size_t)b * NW * NC;
                    #pragma unroll
                    for (int r = 0; r < 4; ++r) {
                        const int w = w0 + 2*(g*4 + r) + mt;
                        dst[(size_t)w * NC + o] = (__bf16)(s[r] + bb);
                    }
                } else {
                    __bf16* dst = V + ((size_t)b * NC + o) * NW;
                    #pragma unroll
                    for (int r = 0; r < 4; ++r) {
                        const int w = w0 + 2*(g*4 + r) + mt;
                        dst[w] = (__bf16)(s[r] + bb);
                    }
                }
            }
        }
    }
}

// ---------------------------------------------------------------------------
// Kernel 2: flash attention on 32x32x16 MFMA.  (unchanged from R4 - verified)
// K rows fed to QK^T are sigma-permuted (swap row-quads 1<->2, 5<->6) so that
// S output row m carries v = sigma(m); with the C/D map
// row=(r&3)+8*(r>>2)+4*hi this makes each lane's 16 scores v-CONTIGUOUS:
// hi=0 owns v {0..7,16..23}, hi=1 owns {8..15,24..31} == exactly the PV
// B-fragment slots (k=8*hi+j). P assembly = 8 local pk2, ZERO cross-lane ops.
// ---------------------------------------------------------------------------
__global__ __launch_bounds__(512) void attn_kernel(
    const float* __restrict__ x,
    const __bf16* __restrict__ qT, const __bf16* __restrict__ kT,
    const __bf16* __restrict__ V,
    float* __restrict__ out)
{
    const int b    = blockIdx.x >> 6;
    const int wt   = blockIdx.x & 63;
    const int w0   = wt * 32;
    const int wave = threadIdx.x >> 6;        // KV slice 0..7
    const int lane = threadIdx.x & 63;
    const int wl = lane & 31, hi = lane >> 5;
    // sigma: swap bits 2 and 3 of wl (row-quad 1<->2, 5<->6)
    const int swl = (wl & 0x13) | ((wl & 4) << 1) | ((wl & 8) >> 1);

    const __bf16* qTb = qT + (size_t)b * NW * NC;
    const __bf16* kTb = kT + (size_t)b * NW * NC;
    const __bf16* Vb  = V  + (size_t)b * NC * NW;

    // Q fragments (B-operand): col n = w0+wl, channel slots c = 8*hi+j (+16)
    const __bf16* qrow = qTb + (size_t)(w0 + wl) * NC;
    const bf16x8 qf0 = *(const bf16x8*)(qrow + hi*8);
    const bf16x8 qf1 = *(const bf16x8*)(qrow + 16 + hi*8);

    f32x16 acc, z16;
    #pragma unroll
    for (int r = 0; r < 16; ++r) { acc[r] = 0.f; z16[r] = 0.f; }
    float m = -1e30f, lsum = 0.f;

    const int vbeg = wave * 256;
    for (int it = 0; it < 8; ++it) {
        const int v0 = vbeg + it * 32;
        const __bf16* krow = kTb + (size_t)(v0 + swl) * NC;   // sigma-permuted
        const bf16x8 kf0 = *(const bf16x8*)(krow + hi*8);
        const bf16x8 kf1 = *(const bf16x8*)(krow + 16 + hi*8);
        const __bf16* vrow = Vb + (size_t)wl * NW + v0;
        const bf16x8 vf0 = *(const bf16x8*)(vrow + hi*8);
        const bf16x8 vf1 = *(const bf16x8*)(vrow + 16 + hi*8);

        f32x16 s = __builtin_amdgcn_mfma_f32_32x32x16_bf16(kf0, qf0, z16, 0, 0, 0);
        s = __builtin_amdgcn_mfma_f32_32x32x16_bf16(kf1, qf1, s, 0, 0, 0);
        // lane (wl,hi) now holds P-scores for v-set: p[r] <-> v = (hi? 8:0)+r
        // for r<8, and v = 16+(hi?8:0)+(r-8) for r>=8  (v-contiguous blocks)

        // ---- online softmax over v for this lane's query column ----
        float tm[8];
        #pragma unroll
        for (int r = 0; r < 8; ++r) tm[r] = fmaxf(s[r], s[r+8]);
        #pragma unroll
        for (int r = 0; r < 4; ++r) tm[r] = fmaxf(tm[r], tm[r+4]);
        float vm = fmaxf(fmaxf(tm[0], tm[1]), fmaxf(tm[2], tm[3]));
        vm = fmaxf(vm, __shfl_xor(vm, 32));
        const float nm = fmaxf(m, vm);
        const float sc = __expf(m - nm);
        float p[16];
        #pragma unroll
        for (int r = 0; r < 16; ++r) p[r] = __expf(s[r] - nm);
        float ts[8];
        #pragma unroll
        for (int r = 0; r < 8; ++r) ts[r] = p[r] + p[r+8];
        #pragma unroll
        for (int r = 0; r < 4; ++r) ts[r] += ts[r+4];
        float ps = (ts[0] + ts[1]) + (ts[2] + ts[3]);
        ps += __shfl_xor(ps, 32);
        lsum = lsum * sc + ps;
        m = nm;
        #pragma unroll
        for (int r = 0; r < 16; ++r) acc[r] *= sc;

        // ---- PV B-fragments: purely lane-local after the sigma trick ----
        union { unsigned int u[4]; bf16x8 v; } pf1, pf2;
        #pragma unroll
        for (int i = 0; i < 4; ++i) pf1.u[i] = pk2(p[2*i],     p[2*i + 1]);
        #pragma unroll
        for (int i = 0; i < 4; ++i) pf2.u[i] = pk2(p[8 + 2*i], p[8 + 2*i + 1]);

        acc = __builtin_amdgcn_mfma_f32_32x32x16_bf16(vf0, pf1.v, acc, 0, 0, 0);
        acc = __builtin_amdgcn_mfma_f32_32x32x16_bf16(vf1, pf2.v, acc, 0, 0, 0);
    }

    // ---- merge the 8 KV slices (exact flash combine) ----
    __shared__ float sm[8][32];
    __shared__ float sl[8][32];
    __shared__ float sO[8][32][33];
    __shared__ float Of[32][33];

    if (hi == 0) { sm[wave][wl] = m; sl[wave][wl] = lsum; }
    #pragma unroll
    for (int r = 0; r < 16; ++r) {
        const int c = (r & 3) + 8*(r >> 2) + 4*hi;
        sO[wave][c][wl] = acc[r];
    }
    __syncthreads();

    {
        const int w  = threadIdx.x & 31;
        const int c0 = (threadIdx.x >> 5) * 2;
        float ms[8], ls[8], f[8];
        #pragma unroll
        for (int s = 0; s < 8; ++s) { ms[s] = sm[s][w]; ls[s] = sl[s][w]; }
        float M = ms[0];
        #pragma unroll
        for (int s = 1; s < 8; ++s) M = fmaxf(M, ms[s]);
        float L = 0.f;
        #pragma unroll
        for (int s = 0; s < 8; ++s) { f[s] = __expf(ms[s] - M); L += ls[s] * f[s]; }
        const float rL = 1.0f / L;
        #pragma unroll
        for (int cc = 0; cc < 2; ++cc) {
            float o = 0.f;
            #pragma unroll
            for (int s = 0; s < 8; ++s) o += sO[s][c0 + cc][w] * f[s];
            Of[c0 + cc][w] = o * rL;
        }
    }
    __syncthreads();

    // ---- block-wide epilogue: out[b,c,h,w0..w0+31] = Of[c][.] + x ----
    const float* xb = x   + (size_t)b * NC * NH * NW + w0;
    float*       ob = out + (size_t)b * NC * NH * NW + w0;
    const int chunk = threadIdx.x & 7;          // 4 floats each
    #pragma unroll
    for (int it = 0; it < 16; ++it) {
        const int row = it*64 + (threadIdx.x >> 3);   // 0..1023 = c*32+h
        const int c = row >> 5, h = row & 31;
        const size_t off = ((size_t)c * NH + h) * NW + chunk*4;
        const float4 xv = *(const float4*)(xb + off);
        float4 ov;
        ov.x = Of[c][chunk*4 + 0] + xv.x;
        ov.y = Of[c][chunk*4 + 1] + xv.y;
        ov.z = Of[c][chunk*4 + 2] + xv.z;
        ov.w = Of[c][chunk*4 + 3] + xv.w;
        *(float4*)(ob + off) = ov;
    }
}

extern "C" void kernel_launch(void* const* d_in, const int* in_sizes, int n_in,
                              void* d_out, int out_size, void* d_ws, size_t ws_size,
                              hipStream_t stream)
{
    const float* x  = (const float*)d_in[0];
    const float* wq = (const float*)d_in[1];
    const float* bq = (const float*)d_in[2];
    const float* wk = (const float*)d_in[3];
    const float* bk = (const float*)d_in[4];
    const float* wv = (const float*)d_in[5];
    const float* bv = (const float*)d_in[6];
    float* out = (float*)d_out;

    // ws layout (bf16): qT [B][W][32] @0, kT @2MB, V [B][32][W] @4MB, wb @6MB
    char* ws = (char*)d_ws;
    __bf16* qT = (__bf16*)(ws);
    __bf16* kT = (__bf16*)(ws + (2u << 20));
    __bf16* V  = (__bf16*)(ws + (4u << 20));
    __bf16* wb = (__bf16*)(ws + (6u << 20));

    hipLaunchKernelGGL(wprep_kernel, dim3(96), dim3(256), 0, stream, wq, wk, wv, wb);
    hipLaunchKernelGGL(proj_kernel, dim3(NB * 64), dim3(256), 0, stream,
                       x, wb, bq, bk, bv, qT, kT, V);
    hipLaunchKernelGGL(attn_kernel, dim3(NB * 64), dim3(512), 0, stream,
                       x, qT, kT, V, out);
}

// Round 6
// 101.930 us; speedup vs baseline: 1.5573x; 1.0093x over previous
//
#include <hip/hip_runtime.h>
#include <hip/hip_bf16.h>

typedef __bf16 bf16x8 __attribute__((ext_vector_type(8)));
typedef float  f32x4  __attribute__((ext_vector_type(4)));
typedef float  f32x16 __attribute__((ext_vector_type(16)));

#define NB 16
#define NC 32
#define NH 32
#define NW 2048
#define NK (NC*NH)   // 1024

static __device__ __forceinline__ unsigned int pk2(float a, float b) {
    union { __bf16 h[2]; unsigned int u; } z;
    z.h[0] = (__bf16)a; z.h[1] = (__bf16)b;
    return z.u;
}

// ---------------------------------------------------------------------------
// Kernel 0: weights -> bf16. wb layout [3][32][1024].
// ---------------------------------------------------------------------------
__global__ __launch_bounds__(256) void wprep_kernel(
    const float* __restrict__ wq, const float* __restrict__ wk,
    const float* __restrict__ wv, __bf16* __restrict__ wb)
{
    const int i = blockIdx.x * 256 + threadIdx.x;        // 24576 float4 units
    const float* srcs[3] = { wq, wk, wv };
    const float4 v = *(const float4*)(srcs[i >> 13] + (size_t)(i & 8191) * 4);
    union { __bf16 h[4]; unsigned long long u; } z;
    z.h[0] = (__bf16)v.x; z.h[1] = (__bf16)v.y;
    z.h[2] = (__bf16)v.z; z.h[3] = (__bf16)v.w;
    *(unsigned long long*)(wb + (size_t)i * 4) = z.u;
}

// ---------------------------------------------------------------------------
// Kernel 1: QKV projection, 4-way K-split, LDS-staged A (the fix).
// Each wave owns K-slice [wave*256, +256). Per 32k-step it stages its own
// 32k x 32w x-tile: 4 coalesced float4 row-loads per lane (128B lines),
// bf16-convert, transposed write into a PRIVATE [32w][40k] LDS tile
// (16B-aligned rows -> ds_read_b128 A-frags, <=2-way bank aliasing).
// Register + LDS double-buffer; NO barriers in the K-loop (per-wave tiles).
// Combine array is union'd over the staging LDS (24.5 KB total).
// ---------------------------------------------------------------------------
__global__ __launch_bounds__(256) void proj_kernel(
    const float* __restrict__ x, const __bf16* __restrict__ wb,
    const float* __restrict__ bq, const float* __restrict__ bk,
    const float* __restrict__ bv,
    __bf16* __restrict__ qT, __bf16* __restrict__ kT, __bf16* __restrict__ V)
{
    const int b    = blockIdx.x >> 6;
    const int wt   = blockIdx.x & 63;
    const int wave = threadIdx.x >> 6;       // = K slice
    const int lane = threadIdx.x & 63;
    const int g    = lane >> 4;
    const int lr   = lane & 15;
    const int w0   = wt * 32;

    __shared__ __align__(16) char smem_raw[24576];
    // staging view: [wave][buf][w(32)][k(40: 32 + pad to 80B rows)]
    __bf16 (*stage)[2][32][40] = reinterpret_cast<__bf16(*)[2][32][40]>(smem_raw);
    // combine view (used after K-loop, behind a barrier)
    f32x4 (*part)[6][64] = reinterpret_cast<f32x4(*)[6][64]>(smem_raw);

    const float* xb = x + (size_t)b * NK * NW;
    const int k0 = wave * 256;

    // staging map: lane -> (skr = k row within 8-row group, swq = float4 col)
    const int skr = lane >> 3;               // 0..7
    const int swq = lane & 7;                // 0..7 -> w = swq*4 .. +3
    const float* xs = xb + w0 + swq * 4;

    f32x4 acc[2][6];
    #pragma unroll
    for (int mt = 0; mt < 2; ++mt)
        #pragma unroll
        for (int nt = 0; nt < 6; ++nt)
            acc[mt][nt] = f32x4{0.f, 0.f, 0.f, 0.f};

    float4 xv[4];

#define LOADX(STEP)                                                           \
    _Pragma("unroll")                                                         \
    for (int r4 = 0; r4 < 4; ++r4)                                            \
        xv[r4] = *(const float4*)(xs + (size_t)(k0 + (STEP)*32 + r4*8 + skr) * NW);

#define WRITEX(BUF)                                                           \
    _Pragma("unroll")                                                         \
    for (int r4 = 0; r4 < 4; ++r4) {                                          \
        const int kl = r4*8 + skr;                                            \
        __bf16* wp = &stage[wave][BUF][swq*4][kl];                            \
        wp[0]   = (__bf16)xv[r4].x;                                           \
        wp[40]  = (__bf16)xv[r4].y;                                           \
        wp[80]  = (__bf16)xv[r4].z;                                           \
        wp[120] = (__bf16)xv[r4].w;                                           \
    }

#define COMPUTE(BUF, KK)                                                      \
    {                                                                         \
        const bf16x8 af0 = *(const bf16x8*)&stage[wave][BUF][lr][g*8];        \
        const bf16x8 af1 = *(const bf16x8*)&stage[wave][BUF][16 + lr][g*8];   \
        bf16x8 bfv[6];                                                        \
        _Pragma("unroll")                                                     \
        for (int nt = 0; nt < 6; ++nt)                                        \
            bfv[nt] = *(const bf16x8*)(wb + (size_t)(nt >> 1) * 32768         \
                                          + (size_t)((nt & 1) * 16 + lr) * NK \
                                          + (KK) + g*8);                      \
        _Pragma("unroll")                                                     \
        for (int nt = 0; nt < 6; ++nt) {                                      \
            acc[0][nt] = __builtin_amdgcn_mfma_f32_16x16x32_bf16(             \
                af0, bfv[nt], acc[0][nt], 0, 0, 0);                           \
            acc[1][nt] = __builtin_amdgcn_mfma_f32_16x16x32_bf16(             \
                af1, bfv[nt], acc[1][nt], 0, 0, 0);                           \
        }                                                                     \
    }

    LOADX(0); WRITEX(0);
    LOADX(1);
    #pragma unroll
    for (int s = 0; s < 8; ++s) {
        const int cb = s & 1;
        if (s < 7) { WRITEX(cb ^ 1); }       // stage step s+1 (regs -> LDS)
        if (s < 6) { LOADX(s + 2); }         // issue step s+2 global loads
        COMPUTE(cb, k0 + s*32);
    }
#undef LOADX
#undef WRITEX
#undef COMPUTE

    // ---- combine the 4 K-slices, two mt-rounds through the union'd LDS ----
    const float* biases[3] = { bq, bk, bv };
    #pragma unroll
    for (int mt = 0; mt < 2; ++mt) {
        __syncthreads();                     // also guards stage->part reuse
        #pragma unroll
        for (int nt = 0; nt < 6; ++nt)
            part[wave][nt][lane] = acc[mt][nt];
        __syncthreads();
        #pragma unroll
        for (int q = 0; q < 2; ++q) {
            const int nt = wave + q * 4;
            if (nt < 6) {
                f32x4 s = part[0][nt][lane];
                #pragma unroll
                for (int sl = 1; sl < 4; ++sl) s += part[sl][nt][lane];
                const int pid = nt >> 1;             // 0=q,1=k,2=v
                const int o   = (nt & 1) * 16 + lr;
                const float bb = biases[pid][o];
                if (pid < 2) {
                    __bf16* dst = (pid ? kT : qT) + (size_t)b * NW * NC;
                    #pragma unroll
                    for (int r = 0; r < 4; ++r) {
                        const int w = w0 + mt*16 + g*4 + r;
                        dst[(size_t)w * NC + o] = (__bf16)(s[r] + bb);
                    }
                } else {
                    union { __bf16 h[4]; unsigned long long u; } z;
                    #pragma unroll
                    for (int r = 0; r < 4; ++r) z.h[r] = (__bf16)(s[r] + bb);
                    __bf16* dst = V + ((size_t)b * NC + o) * NW + (w0 + mt*16 + g*4);
                    *(unsigned long long*)dst = z.u;
                }
            }
        }
    }
}

// ---------------------------------------------------------------------------
// Kernel 2: flash attention on 32x32x16 MFMA.  (unchanged - verified R4/R5)
// K rows fed to QK^T are sigma-permuted (swap row-quads 1<->2, 5<->6) so that
// S output row m carries v = sigma(m); with the C/D map
// row=(r&3)+8*(r>>2)+4*hi this makes each lane's 16 scores v-CONTIGUOUS:
// hi=0 owns v {0..7,16..23}, hi=1 owns {8..15,24..31} == exactly the PV
// B-fragment slots (k=8*hi+j). P assembly = 8 local pk2, ZERO cross-lane ops.
// ---------------------------------------------------------------------------
__global__ __launch_bounds__(512) void attn_kernel(
    const float* __restrict__ x,
    const __bf16* __restrict__ qT, const __bf16* __restrict__ kT,
    const __bf16* __restrict__ V,
    float* __restrict__ out)
{
    const int b    = blockIdx.x >> 6;
    const int wt   = blockIdx.x & 63;
    const int w0   = wt * 32;
    const int wave = threadIdx.x >> 6;        // KV slice 0..7
    const int lane = threadIdx.x & 63;
    const int wl = lane & 31, hi = lane >> 5;
    // sigma: swap bits 2 and 3 of wl (row-quad 1<->2, 5<->6)
    const int swl = (wl & 0x13) | ((wl & 4) << 1) | ((wl & 8) >> 1);

    const __bf16* qTb = qT + (size_t)b * NW * NC;
    const __bf16* kTb = kT + (size_t)b * NW * NC;
    const __bf16* Vb  = V  + (size_t)b * NC * NW;

    // Q fragments (B-operand): col n = w0+wl, channel slots c = 8*hi+j (+16)
    const __bf16* qrow = qTb + (size_t)(w0 + wl) * NC;
    const bf16x8 qf0 = *(const bf16x8*)(qrow + hi*8);
    const bf16x8 qf1 = *(const bf16x8*)(qrow + 16 + hi*8);

    f32x16 acc, z16;
    #pragma unroll
    for (int r = 0; r < 16; ++r) { acc[r] = 0.f; z16[r] = 0.f; }
    float m = -1e30f, lsum = 0.f;

    const int vbeg = wave * 256;
    for (int it = 0; it < 8; ++it) {
        const int v0 = vbeg + it * 32;
        const __bf16* krow = kTb + (size_t)(v0 + swl) * NC;   // sigma-permuted
        const bf16x8 kf0 = *(const bf16x8*)(krow + hi*8);
        const bf16x8 kf1 = *(const bf16x8*)(krow + 16 + hi*8);
        const __bf16* vrow = Vb + (size_t)wl * NW + v0;
        const bf16x8 vf0 = *(const bf16x8*)(vrow + hi*8);
        const bf16x8 vf1 = *(const bf16x8*)(vrow + 16 + hi*8);

        f32x16 s = __builtin_amdgcn_mfma_f32_32x32x16_bf16(kf0, qf0, z16, 0, 0, 0);
        s = __builtin_amdgcn_mfma_f32_32x32x16_bf16(kf1, qf1, s, 0, 0, 0);
        // lane (wl,hi) now holds P-scores for v-set: p[r] <-> v = (hi? 8:0)+r
        // for r<8, and v = 16+(hi?8:0)+(r-8) for r>=8  (v-contiguous blocks)

        // ---- online softmax over v for this lane's query column ----
        float tm[8];
        #pragma unroll
        for (int r = 0; r < 8; ++r) tm[r] = fmaxf(s[r], s[r+8]);
        #pragma unroll
        for (int r = 0; r < 4; ++r) tm[r] = fmaxf(tm[r], tm[r+4]);
        float vm = fmaxf(fmaxf(tm[0], tm[1]), fmaxf(tm[2], tm[3]));
        vm = fmaxf(vm, __shfl_xor(vm, 32));
        const float nm = fmaxf(m, vm);
        const float sc = __expf(m - nm);
        float p[16];
        #pragma unroll
        for (int r = 0; r < 16; ++r) p[r] = __expf(s[r] - nm);
        float ts[8];
        #pragma unroll
        for (int r = 0; r < 8; ++r) ts[r] = p[r] + p[r+8];
        #pragma unroll
        for (int r = 0; r < 4; ++r) ts[r] += ts[r+4];
        float ps = (ts[0] + ts[1]) + (ts[2] + ts[3]);
        ps += __shfl_xor(ps, 32);
        lsum = lsum * sc + ps;
        m = nm;
        #pragma unroll
        for (int r = 0; r < 16; ++r) acc[r] *= sc;

        // ---- PV B-fragments: purely lane-local after the sigma trick ----
        union { unsigned int u[4]; bf16x8 v; } pf1, pf2;
        #pragma unroll
        for (int i = 0; i < 4; ++i) pf1.u[i] = pk2(p[2*i],     p[2*i + 1]);
        #pragma unroll
        for (int i = 0; i < 4; ++i) pf2.u[i] = pk2(p[8 + 2*i], p[8 + 2*i + 1]);

        acc = __builtin_amdgcn_mfma_f32_32x32x16_bf16(vf0, pf1.v, acc, 0, 0, 0);
        acc = __builtin_amdgcn_mfma_f32_32x32x16_bf16(vf1, pf2.v, acc, 0, 0, 0);
    }

    // ---- merge the 8 KV slices (exact flash combine) ----
    __shared__ float sm[8][32];
    __shared__ float sl[8][32];
    __shared__ float sO[8][32][33];
    __shared__ float Of[32][33];

    if (hi == 0) { sm[wave][wl] = m; sl[wave][wl] = lsum; }
    #pragma unroll
    for (int r = 0; r < 16; ++r) {
        const int c = (r & 3) + 8*(r >> 2) + 4*hi;
        sO[wave][c][wl] = acc[r];
    }
    __syncthreads();

    {
        const int w  = threadIdx.x & 31;
        const int c0 = (threadIdx.x >> 5) * 2;
        float ms[8], ls[8], f[8];
        #pragma unroll
        for (int s = 0; s < 8; ++s) { ms[s] = sm[s][w]; ls[s] = sl[s][w]; }
        float M = ms[0];
        #pragma unroll
        for (int s = 1; s < 8; ++s) M = fmaxf(M, ms[s]);
        float L = 0.f;
        #pragma unroll
        for (int s = 0; s < 8; ++s) { f[s] = __expf(ms[s] - M); L += ls[s] * f[s]; }
        const float rL = 1.0f / L;
        #pragma unroll
        for (int cc = 0; cc < 2; ++cc) {
            float o = 0.f;
            #pragma unroll
            for (int s = 0; s < 8; ++s) o += sO[s][c0 + cc][w] * f[s];
            Of[c0 + cc][w] = o * rL;
        }
    }
    __syncthreads();

    // ---- block-wide epilogue: out[b,c,h,w0..w0+31] = Of[c][.] + x ----
    const float* xb = x   + (size_t)b * NC * NH * NW + w0;
    float*       ob = out + (size_t)b * NC * NH * NW + w0;
    const int chunk = threadIdx.x & 7;          // 4 floats each
    #pragma unroll
    for (int it = 0; it < 16; ++it) {
        const int row = it*64 + (threadIdx.x >> 3);   // 0..1023 = c*32+h
        const int c = row >> 5, h = row & 31;
        const size_t off = ((size_t)c * NH + h) * NW + chunk*4;
        const float4 xv = *(const float4*)(xb + off);
        float4 ov;
        ov.x = Of[c][chunk*4 + 0] + xv.x;
        ov.y = Of[c][chunk*4 + 1] + xv.y;
        ov.z = Of[c][chunk*4 + 2] + xv.z;
        ov.w = Of[c][chunk*4 + 3] + xv.w;
        *(float4*)(ob + off) = ov;
    }
}

extern "C" void kernel_launch(void* const* d_in, const int* in_sizes, int n_in,
                              void* d_out, int out_size, void* d_ws, size_t ws_size,
                              hipStream_t stream)
{
    const float* x  = (const float*)d_in[0];
    const float* wq = (const float*)d_in[1];
    const float* bq = (const float*)d_in[2];
    const float* wk = (const float*)d_in[3];
    const float* bk = (const float*)d_in[4];
    const float* wv = (const float*)d_in[5];
    const float* bv = (const float*)d_in[6];
    float* out = (float*)d_out;

    // ws layout (bf16): qT [B][W][32] @0, kT @2MB, V [B][32][W] @4MB, wb @6MB
    char* ws = (char*)d_ws;
    __bf16* qT = (__bf16*)(ws);
    __bf16* kT = (__bf16*)(ws + (2u << 20));
    __bf16* V  = (__bf16*)(ws + (4u << 20));
    __bf16* wb = (__bf16*)(ws + (6u << 20));

    hipLaunchKernelGGL(wprep_kernel, dim3(96), dim3(256), 0, stream, wq, wk, wv, wb);
    hipLaunchKernelGGL(proj_kernel, dim3(NB * 64), dim3(256), 0, stream,
                       x, wb, bq, bk, bv, qT, kT, V);
    hipLaunchKernelGGL(attn_kernel, dim3(NB * 64), dim3(512), 0, stream,
                       x, qT, kT, V, out);
}